// Round 1
// baseline (657.221 us; speedup 1.0000x reference)
//
#include <hip/hip_runtime.h>

// GlobalContrastiveLoss, B=131072, D=512, N=1, fp32 in, fp32 scalar out.
// N==1 makes the cosine/argmax branch dead; loss_b = log1p(exp((dn-dp)/50)).
// Memory-bound: 805 MB read -> ~115-130 us floor (HBM 6.3 TB/s + L3-resident part).
//
// Layout: 16 lanes per row, 4 rows per wave.
//  - 24 independent float4 loads in flight per wave-iteration (vs 6 before)
//  - cross-lane reduce: 4 shfl_xor levels, amortized across 4 rows at once
//    (vs 6 levels x 1 row before)
//  - log1p/exp runs on 4 lanes/wave concurrently (vs 1)

#define BLOCK 256
#define WAVES_PER_BLOCK (BLOCK / 64)
#define NBLOCKS 2048
#define DCOLS 512
#define F4_PER_ROW (DCOLS / 4)                 // 128 float4 per row
#define LANES_PER_ROW 16
#define ROWS_PER_WAVE (64 / LANES_PER_ROW)     // 4
#define K_STEPS (F4_PER_ROW / LANES_PER_ROW)   // 8 float4 per lane per stream

__global__ __launch_bounds__(BLOCK) void gcl_partial_kernel(
    const float* __restrict__ img,
    const float* __restrict__ pos,
    const float* __restrict__ neg,
    float* __restrict__ partials,
    int B)
{
    const int lane  = threadIdx.x & 63;
    const int wave  = threadIdx.x >> 6;
    const int j     = lane & (LANES_PER_ROW - 1);   // position within row
    const int g     = lane >> 4;                    // which of the 4 rows
    const int gwave = blockIdx.x * WAVES_PER_BLOCK + wave;
    const int nwaves = gridDim.x * WAVES_PER_BLOCK;

    float acc = 0.0f;

    for (int rbase = gwave * ROWS_PER_WAVE; rbase < B; rbase += nwaves * ROWS_PER_WAVE) {
        int row = rbase + g;
        int row_c = row < B ? row : (B - 1);        // clamp (B%4==0 in practice)

        // float4 index of this lane's first element in its row
        const size_t base = (size_t)row_c * F4_PER_ROW + j;
        const float4* i4 = (const float4*)img + base;
        const float4* p4 = (const float4*)pos + base;
        const float4* n4 = (const float4*)neg + base;

        // Issue all 24 loads up front -> deep MLP; compiler staggers vmcnt waits.
        float4 a[K_STEPS], b[K_STEPS], c[K_STEPS];
        #pragma unroll
        for (int k = 0; k < K_STEPS; ++k) {
            a[k] = i4[(size_t)k * LANES_PER_ROW];
            b[k] = p4[(size_t)k * LANES_PER_ROW];
            c[k] = n4[(size_t)k * LANES_PER_ROW];
        }

        // Two accumulators per dot to break the serial FMA chain.
        float dp0 = 0.0f, dp1 = 0.0f, dn0 = 0.0f, dn1 = 0.0f;
        #pragma unroll
        for (int k = 0; k < K_STEPS; k += 2) {
            dp0 += a[k].x * b[k].x + a[k].y * b[k].y + a[k].z * b[k].z + a[k].w * b[k].w;
            dn0 += a[k].x * c[k].x + a[k].y * c[k].y + a[k].z * c[k].z + a[k].w * c[k].w;
            dp1 += a[k+1].x * b[k+1].x + a[k+1].y * b[k+1].y + a[k+1].z * b[k+1].z + a[k+1].w * b[k+1].w;
            dn1 += a[k+1].x * c[k+1].x + a[k+1].y * c[k+1].y + a[k+1].z * c[k+1].z + a[k+1].w * c[k+1].w;
        }
        float dp = dp0 + dp1;
        float dn = dn0 + dn1;

        // Reduce within each 16-lane group; all 4 rows reduce concurrently.
        #pragma unroll
        for (int off = 8; off >= 1; off >>= 1) {
            dp += __shfl_xor(dp, off, 64);
            dn += __shfl_xor(dn, off, 64);
        }

        if (j == 0 && row < B) {
            // -log(ep/(ep+en)) = log1p(exp((dn-dp)/50))
            acc += log1pf(__expf((dn - dp) * 0.02f));
        }
    }

    // Wave-wide sum (only j==0 lanes hold nonzero), then block sum.
    #pragma unroll
    for (int off = 32; off >= 1; off >>= 1) acc += __shfl_xor(acc, off, 64);

    __shared__ float sacc[WAVES_PER_BLOCK];
    if (lane == 0) sacc[wave] = acc;
    __syncthreads();

    if (threadIdx.x == 0) {
        float s = 0.0f;
        #pragma unroll
        for (int w = 0; w < WAVES_PER_BLOCK; ++w) s += sacc[w];
        partials[blockIdx.x] = s;
    }
}

__global__ __launch_bounds__(256) void gcl_final_kernel(
    const float* __restrict__ partials, int n, float* __restrict__ out, float invB)
{
    __shared__ float s[256];
    float a = 0.0f;
    for (int i = threadIdx.x; i < n; i += 256) a += partials[i];
    s[threadIdx.x] = a;
    __syncthreads();
    #pragma unroll
    for (int stride = 128; stride > 0; stride >>= 1) {
        if (threadIdx.x < stride) s[threadIdx.x] += s[threadIdx.x + stride];
        __syncthreads();
    }
    if (threadIdx.x == 0) out[0] = s[0] * invB;
}

extern "C" void kernel_launch(void* const* d_in, const int* in_sizes, int n_in,
                              void* d_out, int out_size, void* d_ws, size_t ws_size,
                              hipStream_t stream) {
    const float* img = (const float*)d_in[0];
    const float* pos = (const float*)d_in[1];
    const float* neg = (const float*)d_in[2];
    float* out = (float*)d_out;
    float* partials = (float*)d_ws;

    const int B = in_sizes[0] / DCOLS;  // N == 1

    int nblocks = NBLOCKS;
    if (ws_size < (size_t)nblocks * sizeof(float)) {
        nblocks = (int)(ws_size / sizeof(float));  // safety; ws is ample in practice
        if (nblocks < 1) nblocks = 1;
    }

    gcl_partial_kernel<<<nblocks, BLOCK, 0, stream>>>(img, pos, neg, partials, B);
    gcl_final_kernel<<<1, 256, 0, stream>>>(partials, nblocks, out, 1.0f / (float)B);
}

// Round 2
// 616.230 us; speedup vs baseline: 1.0665x; 1.0665x over previous
//
#include <hip/hip_runtime.h>

// GlobalContrastiveLoss, B=131072, D=512, N=1, fp32 in, fp32 scalar out.
// N==1 makes the cosine/argmax branch dead; loss_b = log1p(exp((dn-dp)/50)).
//
// Round-2 theory: two structurally different kernels both plateau at
// 805 MB / ~200 us = 4.03 TB/s of L2-fill traffic (50% L3 hit). Either
// (a) the fabric read path caps ~4 TB/s (then this is the roofline), or
// (b) L3 allocate/evict churn throttles the miss path (402 MB @ 1.9 TB/s
//     = the observed 200 us). Discriminator: nontemporal loads -> no
// L2/L3 allocation, all 805 MB streamed from HBM at pure-read rate.
// Structure reverted to the round-0 layout (1 row/wave, 64 lanes), which
// was the faster variant; extra ILP was proven worthless at this wall.

#define BLOCK 256
#define WAVES_PER_BLOCK (BLOCK / 64)
#define NBLOCKS 2048
#define DCOLS 512

typedef float f32x4 __attribute__((ext_vector_type(4)));

__global__ __launch_bounds__(BLOCK) void gcl_partial_kernel(
    const float* __restrict__ img,
    const float* __restrict__ pos,
    const float* __restrict__ neg,
    float* __restrict__ partials,
    int B)
{
    const int lane  = threadIdx.x & 63;
    const int wave  = threadIdx.x >> 6;
    const int gwave = blockIdx.x * WAVES_PER_BLOCK + wave;
    const int nwaves = gridDim.x * WAVES_PER_BLOCK;

    float acc = 0.0f;

    for (int row = gwave; row < B; row += nwaves) {
        const size_t base = (size_t)row * DCOLS;
        const f32x4* i4 = (const f32x4*)(img + base);
        const f32x4* p4 = (const f32x4*)(pos + base);
        const f32x4* n4 = (const f32x4*)(neg + base);

        // 512 floats/row = 128 float4; 64 lanes x 2 iterations, coalesced.
        // Nontemporal: streaming data, zero reuse within a dispatch; avoid
        // L2/L3 allocation churn entirely.
        f32x4 a0 = __builtin_nontemporal_load(i4 + lane);
        f32x4 a1 = __builtin_nontemporal_load(i4 + lane + 64);
        f32x4 b0 = __builtin_nontemporal_load(p4 + lane);
        f32x4 b1 = __builtin_nontemporal_load(p4 + lane + 64);
        f32x4 c0 = __builtin_nontemporal_load(n4 + lane);
        f32x4 c1 = __builtin_nontemporal_load(n4 + lane + 64);

        float dp = a0.x * b0.x + a0.y * b0.y + a0.z * b0.z + a0.w * b0.w
                 + a1.x * b1.x + a1.y * b1.y + a1.z * b1.z + a1.w * b1.w;
        float dn = a0.x * c0.x + a0.y * c0.y + a0.z * c0.z + a0.w * c0.w
                 + a1.x * c1.x + a1.y * c1.y + a1.z * c1.z + a1.w * c1.w;

        // Wave-wide butterfly reduction (64 lanes).
        #pragma unroll
        for (int off = 32; off >= 1; off >>= 1) {
            dp += __shfl_xor(dp, off, 64);
            dn += __shfl_xor(dn, off, 64);
        }

        if (lane == 0) {
            // -log(ep/(ep+en)) = log1p(exp((dn-dp)/50))
            acc += log1pf(__expf((dn - dp) * 0.02f));
        }
    }

    __shared__ float sacc[WAVES_PER_BLOCK];
    if (lane == 0) sacc[wave] = acc;
    __syncthreads();

    if (threadIdx.x == 0) {
        float s = 0.0f;
        #pragma unroll
        for (int w = 0; w < WAVES_PER_BLOCK; ++w) s += sacc[w];
        partials[blockIdx.x] = s;
    }
}

__global__ __launch_bounds__(256) void gcl_final_kernel(
    const float* __restrict__ partials, int n, float* __restrict__ out, float invB)
{
    __shared__ float s[256];
    float a = 0.0f;
    for (int i = threadIdx.x; i < n; i += 256) a += partials[i];
    s[threadIdx.x] = a;
    __syncthreads();
    #pragma unroll
    for (int stride = 128; stride > 0; stride >>= 1) {
        if (threadIdx.x < stride) s[threadIdx.x] += s[threadIdx.x + stride];
        __syncthreads();
    }
    if (threadIdx.x == 0) out[0] = s[0] * invB;
}

extern "C" void kernel_launch(void* const* d_in, const int* in_sizes, int n_in,
                              void* d_out, int out_size, void* d_ws, size_t ws_size,
                              hipStream_t stream) {
    const float* img = (const float*)d_in[0];
    const float* pos = (const float*)d_in[1];
    const float* neg = (const float*)d_in[2];
    float* out = (float*)d_out;
    float* partials = (float*)d_ws;

    const int B = in_sizes[0] / DCOLS;  // N == 1

    int nblocks = NBLOCKS;
    if (ws_size < (size_t)nblocks * sizeof(float)) {
        nblocks = (int)(ws_size / sizeof(float));  // safety; ws is ample in practice
        if (nblocks < 1) nblocks = 1;
    }

    gcl_partial_kernel<<<nblocks, BLOCK, 0, stream>>>(img, pos, neg, partials, B);
    gcl_final_kernel<<<1, 256, 0, stream>>>(partials, nblocks, out, 1.0f / (float)B);
}